// Round 10
// baseline (1713.776 us; speedup 1.0000x reference)
//
#include <hip/hip_runtime.h>
#include <hip/hip_fp16.h>

#define B_   32
#define S_   256
#define EMB_ 512
#define H_   1024
#define G4_  4096
#define NL_  5
#define NBLK 128

typedef _Float16 f16x8 __attribute__((ext_vector_type(8)));
typedef float f32x4 __attribute__((ext_vector_type(4)));
typedef unsigned long long ull;

__device__ inline ull ldq(const ull* p) {
  return __hip_atomic_load(p, __ATOMIC_RELAXED, __HIP_MEMORY_SCOPE_AGENT);
}
__device__ inline void stw(unsigned* p, unsigned v) {
  __hip_atomic_store(p, v, __ATOMIC_RELAXED, __HIP_MEMORY_SCOPE_AGENT);
}

// ---------------------------------------------------------------------------
// K0: transpose src [K][4096] -> dst [4096][K]. grid (128, K/32).
__global__ __launch_bounds__(256) void k_transposeK(const float* __restrict__ src,
                                                    float* __restrict__ dst, int K) {
  __shared__ float tile[32][33];
  int c0 = blockIdx.x * 32, k0 = blockIdx.y * 32;
  int tx = threadIdx.x & 31, ty = threadIdx.x >> 5;
#pragma unroll
  for (int i = 0; i < 4; ++i)
    tile[ty + 8 * i][tx] = src[(size_t)(k0 + ty + 8 * i) * G4_ + c0 + tx];
  __syncthreads();
#pragma unroll
  for (int i = 0; i < 4; ++i)
    dst[(size_t)(c0 + ty + 8 * i) * K + k0 + tx] = tile[tx][ty + 8 * i];
}

// ---------------------------------------------------------------------------
// K0b: U -> fp16 MFMA B-fragments, planes: hi = fp16(U), lo = fp16((U-hi)*1024).
// Same fragment indexing as the proven bf16 k_prep:
// Ubf[((ug*4 + ks)*8 + s8)*128 + plane*64 + l]: value U[k][gcol],
// k = ks*256 + s8*32 + (l>>4)*8 + j, n16=l&15, gcol=(n16&3)*1024 + ug*4 + (n16>>2).
__global__ __launch_bounds__(256) void k_prepU16(const float* __restrict__ Ut,
                                                 f16x8* __restrict__ Ubf) {
  int gid = blockIdx.x * 256 + threadIdx.x;
  int l = gid & 63;
  int bxws = gid >> 6;
  int n = l & 15, kgrp = l >> 4;
  int s = bxws & 7, bw = bxws >> 3;
  int w = bw & 3, bx = bw >> 2;
  int g = n & 3, ju = n >> 2;
  int gcol = g * 1024 + bx * 4 + ju;
  int kbase = w * 256 + s * 32 + kgrp * 8;
  const float4* f = (const float4*)(Ut + (size_t)gcol * H_ + kbase);
  float4 f0 = f[0], f1 = f[1];
  float v[8] = {f0.x, f0.y, f0.z, f0.w, f1.x, f1.y, f1.z, f1.w};
  f16x8 vh, vl;
#pragma unroll
  for (int j = 0; j < 8; ++j) {
    _Float16 hi = (_Float16)v[j];
    vh[j] = hi;
    vl[j] = (_Float16)((v[j] - (float)hi) * 1024.f);
  }
  Ubf[(size_t)bxws * 128 + l] = vh;
  Ubf[(size_t)bxws * 128 + 64 + l] = vl;
}

// ---------------------------------------------------------------------------
// K0c: W -> fp16 MFMA B-fragments (single plane). (unchanged, proven)
__global__ __launch_bounds__(256) void k_prepW16(const float* __restrict__ Wt,
                                                 unsigned short* __restrict__ Wf16) {
  int gid = blockIdx.x * 256 + threadIdx.x;   // 262144 total
  int l = gid & 63, fi = gid >> 6;
  int kc = fi & 15, ug = fi >> 4;
  int n16 = l & 15, kgrp = l >> 4;
  int gcol = (n16 & 3) * 1024 + ug * 4 + (n16 >> 2);
  const float4* f = (const float4*)(Wt + (size_t)gcol * 512 + kc * 32 + kgrp * 8);
  float4 f0 = f[0], f1 = f[1];
  float v[8] = {f0.x, f0.y, f0.z, f0.w, f1.x, f1.y, f1.z, f1.w};
  union { unsigned short u[8]; uint4 q; } o;
#pragma unroll
  for (int j = 0; j < 8; ++j) o.u[j] = __half_as_ushort(__float2half_rn(v[j]));
  *(uint4*)(Wf16 + ((size_t)fi * 64 + l) * 8) = o.q;
}

// ---------------------------------------------------------------------------
// K0d: gather emb rows -> Xf16 [256 s][32 b][512 e] fp16. (unchanged, proven)
__global__ __launch_bounds__(256) void k_prepX(const int* __restrict__ tokens,
                                               const float* __restrict__ emb,
                                               unsigned short* __restrict__ Xf16) {
  int gid = blockIdx.x * 256 + threadIdx.x;   // 524288 total
  int seg = gid & 63, row = gid >> 6;
  int s = row >> 5, b = row & 31;
  int tok = tokens[b * 256 + s];
  const float4* f = (const float4*)(emb + (size_t)tok * EMB_ + seg * 8);
  float4 f0 = f[0], f1 = f[1];
  float v[8] = {f0.x, f0.y, f0.z, f0.w, f1.x, f1.y, f1.z, f1.w};
  union { unsigned short u[8]; uint4 q; } o;
#pragma unroll
  for (int j = 0; j < 8; ++j) o.u[j] = __half_as_ushort(__float2half_rn(v[j]));
  *(uint4*)(Xf16 + (size_t)row * 512 + seg * 8) = o.q;
}

// ---------------------------------------------------------------------------
// K2: persistent steps v7 — TAGGED self-validating h exchange, no flags.
// grid 128 x 512 (8 waves). Block bx owns 8 units (32 gate cols); wave w =
// K-slice [w*128,(w+1)*128). h word = (t<<16)|fp16(h_t) stored at A-fragment
// position; consumers poll their own operand words for tag==t-1. U in LDS as
// fp16 hi + fp16 lo*1024 planes; z = acc_hi + accL/1024 (+ fused xz fp16 GEMM
// and fp32 bias). Buffers parity: h_t lives in T[t&1].
// Tag word layout: word idx = m*16384 + chunk*512 + (kgrp*16+row)*8 + j,
// where b = m*16+row, k = chunk*32 + kgrp*8 + j.
__global__ __launch_bounds__(512, 2) void k_steps7(
    const f16x8* __restrict__ Ubf,
    const unsigned short* __restrict__ Wf16,
    const unsigned short* __restrict__ Xf16,
    const float* __restrict__ bias,
    unsigned* __restrict__ T0, unsigned* __restrict__ T1) {
  __shared__ f16x8 UL[8192];      // 128 KB: cg*4096 + pl*2048 + ks*512 + s8*64 + l
  __shared__ float red[4096];     // 16 KB
  __shared__ float zg[1056];      // [b][c] stride 33
  __shared__ float bias_s[32];

  const int tid = threadIdx.x;
  const int bx = blockIdx.x;
  const int l = tid & 63, w = tid >> 6;

  // --- stage U into LDS once ---
#pragma unroll
  for (int i = 0; i < 16; ++i) {
    int flat = i * 512 + tid;
    int ll = flat & 63, s8 = (flat >> 6) & 7, ks = (flat >> 9) & 3;
    int pl = (flat >> 11) & 1, cg = flat >> 12;
    size_t fi = (size_t)((bx * 2 + cg) * 4 + ks) * 8 + s8;
    UL[flat] = Ubf[fi * 128 + pl * 64 + ll];
  }
  if (tid < 32) {
    int cg = tid >> 4, n16 = tid & 15;
    bias_s[tid] = bias[(n16 & 3) * 1024 + (bx * 2 + cg) * 4 + (n16 >> 2)];
  }

  // reducer mapping
  const int e = tid & 255, m = tid >> 8;
  const int n16r = (e >> 2) & 15;
  const int zb = m * 16 + (e >> 6) * 4 + (e & 3);

  // gate mapping (tid<256): b=gb, unit gu; tagged-word store index
  const int gb = tid & 31, gu = tid >> 5;
  const int widx = (gb >> 4) * 16384 + (bx >> 2) * 512 +
                   ((bx & 3) * 16 + (gb & 15)) * 8 + gu;
  const int zrd = gb * 33 + (gu >> 2) * 16 + (gu & 3) * 4;
  float creg = 0.f;

  const int ks_w = w >> 1;
  const int xrow0 = (l & 15) * 512 + (l >> 4) * 8;

  __syncthreads();   // U staged

  for (int t = 0; t < S_; ++t) {
    const ull* R64 = (const ull*)((t & 1) ? T0 : T1);   // h_{t-1}
    unsigned* WrT = (t & 1) ? T1 : T0;                  // h_t

    // ---- xz prelude: acc = x_t @ W (fp16 MFMA), no h dependency ----
    f32x4 acc[2][2], accL[2][2];
#pragma unroll
    for (int cg = 0; cg < 2; ++cg) {
      acc[cg][0] = (f32x4){0.f, 0.f, 0.f, 0.f};
      acc[cg][1] = (f32x4){0.f, 0.f, 0.f, 0.f};
      accL[cg][0] = (f32x4){0.f, 0.f, 0.f, 0.f};
      accL[cg][1] = (f32x4){0.f, 0.f, 0.f, 0.f};
    }
    {
      const unsigned short* Xt = Xf16 + (size_t)t * 16384;
#pragma unroll
      for (int c2 = 0; c2 < 2; ++c2) {
        int kc = w * 2 + c2;
        f16x8 xa0 = *(const f16x8*)(Xt + xrow0 + kc * 32);
        f16x8 xa1 = *(const f16x8*)(Xt + 8192 + xrow0 + kc * 32);
        f16x8 wb0 = *(const f16x8*)(Wf16 + ((size_t)((bx * 2 + 0) * 16 + kc) * 64 + l) * 8);
        f16x8 wb1 = *(const f16x8*)(Wf16 + ((size_t)((bx * 2 + 1) * 16 + kc) * 64 + l) * 8);
        acc[0][0] = __builtin_amdgcn_mfma_f32_16x16x32_f16(xa0, wb0, acc[0][0], 0, 0, 0);
        acc[0][1] = __builtin_amdgcn_mfma_f32_16x16x32_f16(xa1, wb0, acc[0][1], 0, 0, 0);
        acc[1][0] = __builtin_amdgcn_mfma_f32_16x16x32_f16(xa0, wb1, acc[1][0], 0, 0, 0);
        acc[1][1] = __builtin_amdgcn_mfma_f32_16x16x32_f16(xa1, wb1, acc[1][1], 0, 0, 0);
      }
    }

    // ---- recurrence: poll own tagged operand words, then MFMA ----
    if (t > 0) {
      ull A[2][4][4];   // [m][s][i] — 32 ull
      const unsigned tg = (unsigned)(t - 1);
      bool ok;
      do {
#pragma unroll
        for (int m2 = 0; m2 < 2; ++m2)
#pragma unroll
          for (int s = 0; s < 4; ++s) {
            int ib = m2 * 8192 + (w * 4 + s) * 256 + l * 4;
#pragma unroll
            for (int i = 0; i < 4; ++i) A[m2][s][i] = ldq(R64 + ib + i);
          }
        unsigned bad = 0;
#pragma unroll
        for (int m2 = 0; m2 < 2; ++m2)
#pragma unroll
          for (int s = 0; s < 4; ++s)
#pragma unroll
            for (int i = 0; i < 4; ++i) {
              ull q = A[m2][s][i];
              bad |= (((unsigned)(q >> 16)) & 0xffffu) ^ tg;
              bad |= ((unsigned)(q >> 48)) ^ tg;
            }
        ok = __all(bad == 0);
        if (!ok) __builtin_amdgcn_s_sleep(1);
      } while (!ok);

#pragma unroll
      for (int s = 0; s < 4; ++s) {
        int s8 = (w & 1) * 4 + s;
        union { unsigned u[4]; f16x8 v; } a0, a1;
#pragma unroll
        for (int i = 0; i < 4; ++i) {
          ull q0 = A[0][s][i], q1 = A[1][s][i];
          a0.u[i] = ((unsigned)q0 & 0xffffu) | (((unsigned)(q0 >> 16)) & 0xffff0000u);
          a1.u[i] = ((unsigned)q1 & 0xffffu) | (((unsigned)(q1 >> 16)) & 0xffff0000u);
        }
#pragma unroll
        for (int cg = 0; cg < 2; ++cg) {
          f16x8 uhf = UL[cg * 4096 + ks_w * 512 + s8 * 64 + l];
          f16x8 ulf = UL[cg * 4096 + 2048 + ks_w * 512 + s8 * 64 + l];
          acc[cg][0]  = __builtin_amdgcn_mfma_f32_16x16x32_f16(a0.v, uhf, acc[cg][0], 0, 0, 0);
          acc[cg][1]  = __builtin_amdgcn_mfma_f32_16x16x32_f16(a1.v, uhf, acc[cg][1], 0, 0, 0);
          accL[cg][0] = __builtin_amdgcn_mfma_f32_16x16x32_f16(a0.v, ulf, accL[cg][0], 0, 0, 0);
          accL[cg][1] = __builtin_amdgcn_mfma_f32_16x16x32_f16(a1.v, ulf, accL[cg][1], 0, 0, 0);
        }
      }
    }

    // fold lo-plane: z = acc + accL/1024
#pragma unroll
    for (int cg = 0; cg < 2; ++cg) {
      acc[cg][0] += accL[cg][0] * 9.765625e-4f;
      acc[cg][1] += accL[cg][1] * 9.765625e-4f;
    }

    // ---- two-pass reduction ----
    if (w < 4) {
#pragma unroll
      for (int cg = 0; cg < 2; ++cg) {
        *(f32x4*)(&red[((w * 2 + 0) * 2 + cg) * 256 + l * 4]) = acc[cg][0];
        *(f32x4*)(&red[((w * 2 + 1) * 2 + cg) * 256 + l * 4]) = acc[cg][1];
      }
    }
    __syncthreads();
    if (w >= 4) {
      int w4 = w - 4;
#pragma unroll
      for (int cg = 0; cg < 2; ++cg) {
        f32x4* p0 = (f32x4*)(&red[((w4 * 2 + 0) * 2 + cg) * 256 + l * 4]);
        f32x4* p1 = (f32x4*)(&red[((w4 * 2 + 1) * 2 + cg) * 256 + l * 4]);
        *p0 += acc[cg][0];
        *p1 += acc[cg][1];
      }
    }
    __syncthreads();

    // ---- final reduce + fp32 bias -> zg ----
    {
      float z0 = bias_s[n16r], z1 = bias_s[16 + n16r];
#pragma unroll
      for (int w4 = 0; w4 < 4; ++w4) {
        z0 += red[((w4 * 2 + m) * 2 + 0) * 256 + e];
        z1 += red[((w4 * 2 + m) * 2 + 1) * 256 + e];
      }
      zg[zb * 33 + n16r] = z0;
      zg[zb * 33 + 16 + n16r] = z1;
    }
    __syncthreads();

    // ---- gates + tagged fire-and-forget store (no drain, no flag) ----
    if (tid < 256) {
      float zi = zg[zrd + 0];
      float zf = zg[zrd + 1];
      float zc_ = zg[zrd + 2];
      float zo = zg[zrd + 3];
      float ig = 1.f / (1.f + __expf(-zi));
      float fg = 1.f / (1.f + __expf(-zf));
      float gg = tanhf(zc_);
      float og = 1.f / (1.f + __expf(-zo));
      creg = fg * creg + ig * gg;
      float hv = og * tanhf(creg);
      unsigned short h16 = __half_as_ushort(__float2half_rn(hv));
      stw(WrT + widx, ((unsigned)t << 16) | (unsigned)h16);
    }
  }
}

// ---------------------------------------------------------------------------
// K3: logits from tagged fp16 h (t=255 parity -> T1). grid 5, block 256.
__global__ __launch_bounds__(256) void k_head5(const unsigned* __restrict__ T,
                                               const float* __restrict__ Wd,
                                               const float* __restrict__ bd,
                                               float* __restrict__ out) {
  __shared__ float red[32 * 9];
  int lbl = blockIdx.x;
  int tid = threadIdx.x;
  int b = tid >> 3, ks = tid & 7;
  int mb = (b >> 4) * 16384;
  float acc = 0.f;
  for (int k = ks * 128; k < ks * 128 + 128; ++k) {
    int idx = mb + (k >> 5) * 512 + (((k >> 3) & 3) * 16 + (b & 15)) * 8 + (k & 7);
    float hv = __half2float(__ushort_as_half((unsigned short)(T[idx] & 0xffffu)));
    acc += hv * Wd[k * NL_ + lbl];
  }
  red[b * 9 + ks] = acc;
  __syncthreads();
  if (tid < 32) {
    float s = bd[lbl];
#pragma unroll
    for (int i = 0; i < 8; ++i) s += red[tid * 9 + i];
    out[tid * NL_ + lbl] = s;
  }
}

// ---------------------------------------------------------------------------
extern "C" void kernel_launch(void* const* d_in, const int* in_sizes, int n_in,
                              void* d_out, int out_size, void* d_ws, size_t ws_size,
                              hipStream_t stream) {
  const int* tokens  = (const int*)d_in[0];
  const float* emb   = (const float*)d_in[1];
  const float* W     = (const float*)d_in[2];
  const float* U     = (const float*)d_in[3];
  const float* bias  = (const float*)d_in[4];
  const float* Wd    = (const float*)d_in[5];
  const float* bd    = (const float*)d_in[6];
  float* out = (float*)d_out;

  char* ws = (char*)d_ws;
  // Layout (within proven budget):
  //   Xf16 fp16 [256][32][512]  @ 0           (8 MiB)
  //   Wf16 fp16 frags           @ 8,388,608   (4 MiB)
  //   Ut fp32 (transient)       @ 16,777,216  (16 MiB)
  //   Wt fp32 (transient)       @ 33,554,432  (8 MiB)
  //   Ubf fp16 frag planes      @ 67,108,864  (16 MiB)
  //   tagged h: T0, T1 (128 KB each) @ 83,886,080 — memset 0xFF each launch
  unsigned short* Xf16 = (unsigned short*)ws;
  unsigned short* Wf16 = (unsigned short*)(ws + 8388608);
  float* Ut          = (float*)(ws + 16777216);
  float* Wt          = (float*)(ws + 33554432);
  f16x8* Ubf         = (f16x8*)(ws + 67108864);
  unsigned* T0       = (unsigned*)(ws + 83886080);
  unsigned* T1       = (unsigned*)(ws + 83886080 + 131072);

  // clear tags (0xFFFF never a valid step tag) — required every replay
  hipMemsetAsync(T0, 0xFF, 262144, stream);
  k_transposeK<<<dim3(128, 32), 256, 0, stream>>>(U, Ut, 1024);
  k_prepU16<<<2048, 256, 0, stream>>>(Ut, Ubf);
  k_transposeK<<<dim3(128, 16), 256, 0, stream>>>(W, Wt, 512);
  k_prepW16<<<1024, 256, 0, stream>>>(Wt, Wf16);
  k_prepX<<<2048, 256, 0, stream>>>(tokens, emb, Xf16);

  k_steps7<<<NBLK, 512, 0, stream>>>(Ubf, Wf16, Xf16, bias, T0, T1);

  // t=255 (odd) wrote T1
  k_head5<<<NL_, 256, 0, stream>>>(T1, Wd, bd, out);
}